// Round 2
// baseline (20571.619 us; speedup 1.0000x reference)
//
#include <hip/hip_runtime.h>
#include <hip/hip_cooperative_groups.h>
#include <cstdint>
#include <cstddef>

namespace cg = cooperative_groups;

#define Dk 256
#define Hk 512
#define Bk 16
#define Tk 512
#define Gk 2048      // 4H
#define NVk 262144   // H*H

typedef __bf16 bf16;
typedef __bf16 bf16x8 __attribute__((ext_vector_type(8)));
typedef float  f32x4  __attribute__((ext_vector_type(4)));
typedef const __attribute__((address_space(1))) void* gvp;
typedef __attribute__((address_space(3))) void* lvp;

// ---------- prep kernels ----------
__global__ __launch_bounds__(256) void cvt_f32_bf16(const float* __restrict__ in,
                                                    bf16* __restrict__ out, int n8) {
  int i = blockIdx.x * 256 + threadIdx.x;
  if (i >= n8) return;
  const float4* p = reinterpret_cast<const float4*>(in) + (size_t)i * 2;
  float4 a = p[0], b = p[1];
  bf16x8 v;
  v[0] = (bf16)a.x; v[1] = (bf16)a.y; v[2] = (bf16)a.z; v[3] = (bf16)a.w;
  v[4] = (bf16)b.x; v[5] = (bf16)b.y; v[6] = (bf16)b.z; v[7] = (bf16)b.w;
  *reinterpret_cast<bf16x8*>(out + (size_t)i * 8) = v;
}

// V_w[j][d*512+h'] (fp32) -> packed B: V2p[(d/8)][n=(j,h')][d%8] (bf16)
__global__ __launch_bounds__(256) void pack_V(const float* __restrict__ Vw,
                                              bf16* __restrict__ V2p) {
  int n = blockIdx.x * 256 + threadIdx.x;        // 0..262143
  int j = n >> 9, hp = n & 511;
  const float* src = Vw + (size_t)j * 131072 + hp;
  for (int kb = 0; kb < 32; ++kb) {
    bf16x8 v;
#pragma unroll
    for (int r = 0; r < 8; ++r) v[r] = (bf16)src[(size_t)(kb * 8 + r) * 512];
    *reinterpret_cast<bf16x8*>(V2p + ((size_t)kb * NVk + n) * 8) = v;
  }
}

// W_w[g][d] (fp32) -> packed B: Wp[(d/8)][g][d%8] (bf16)
__global__ __launch_bounds__(256) void pack_W(const float* __restrict__ Ww,
                                              bf16* __restrict__ Wp) {
  int g = blockIdx.x * 256 + threadIdx.x;        // 0..2047
  const float* src = Ww + (size_t)g * 256;
  for (int kb = 0; kb < 32; ++kb) {
    bf16x8 v;
#pragma unroll
    for (int r = 0; r < 8; ++r) v[r] = (bf16)src[kb * 8 + r];
    *reinterpret_cast<bf16x8*>(Wp + ((size_t)kb * Gk + g) * 8) = v;
  }
}

// x[row][d] (fp32, row=b*512+t) -> packed A: xp[(d/8)][row][d%8] (bf16)
__global__ __launch_bounds__(256) void pack_x(const float* __restrict__ x,
                                              bf16* __restrict__ xp) {
  int row = blockIdx.x * 256 + threadIdx.x;      // 0..8191
  const float* src = x + (size_t)row * 256;
  for (int kb = 0; kb < 32; ++kb) {
    bf16x8 v;
#pragma unroll
    for (int r = 0; r < 8; ++r) v[r] = (bf16)src[kb * 8 + r];
    *reinterpret_cast<bf16x8*>(xp + ((size_t)kb * 8192 + row) * 8) = v;
  }
}

__global__ __launch_bounds__(256) void init_state(float* __restrict__ hbuf,
                                                  float* __restrict__ cws) {
  int i = blockIdx.x * 256 + threadIdx.x;
  if (i < 16384) hbuf[i] = 0.f;
  if (i < 8192)  cws[i]  = 0.f;
}

// ---------- 128x128 tile MFMA GEMM with global_load_lds staging ----------
// A packed [k/8][Mtot][k%8], row map: b = m>>tcShift ; xrow = b*512 + t0 + (m&tcMask)
// B packed [k/8][N][k%8]
template <bool BF16_OUT>
__global__ __launch_bounds__(256) void gemm128(const bf16* __restrict__ Ap,
                                               const bf16* __restrict__ Bp,
                                               float* __restrict__ outF,
                                               bf16* __restrict__ outB,
                                               const float* __restrict__ bias,
                                               int N, int Mtot,
                                               int t0, int tcMask, int tcShift) {
  __shared__ uint4 a_sm[512];   // [kb(4)][m(128)] 16B each
  __shared__ uint4 b_sm[512];   // [kb(4)][n(128)]
  int tid = threadIdx.x;
  int lane = tid & 63, w = tid >> 6;
  int quad = lane >> 4, l15 = lane & 15;
  int wm = w >> 1, wn = w & 1;
  int m0 = blockIdx.x * 128, n0 = blockIdx.y * 128;

  f32x4 acc[4][4];
#pragma unroll
  for (int i = 0; i < 4; ++i)
#pragma unroll
    for (int j = 0; j < 4; ++j) acc[i][j] = (f32x4){0.f, 0.f, 0.f, 0.f};

  // per-lane global row indices for A staging (loop-invariant)
  int gm0 = m0 + lane, gm1 = m0 + 64 + lane;
  int xr0 = ((gm0 >> tcShift) << 9) + t0 + (gm0 & tcMask);
  int xr1 = ((gm1 >> tcShift) << 9) + t0 + (gm1 & tcMask);
  const uint4* gA = reinterpret_cast<const uint4*>(Ap);
  const uint4* gB = reinterpret_cast<const uint4*>(Bp);

  const bf16x8* aptr = reinterpret_cast<const bf16x8*>(a_sm);
  const bf16x8* bptr = reinterpret_cast<const bf16x8*>(b_sm);

  for (int kk = 0; kk < 8; ++kk) {
    size_t kbg = (size_t)(kk * 4 + w);
    // each wave fills kb=w rows of a_sm/b_sm; dest = base + lane*16
    __builtin_amdgcn_global_load_lds((gvp)(gA + kbg * Mtot + xr0),
                                     (lvp)(&a_sm[w * 128]), 16, 0, 0);
    __builtin_amdgcn_global_load_lds((gvp)(gA + kbg * Mtot + xr1),
                                     (lvp)(&a_sm[w * 128 + 64]), 16, 0, 0);
    __builtin_amdgcn_global_load_lds((gvp)(gB + kbg * N + n0 + lane),
                                     (lvp)(&b_sm[w * 128]), 16, 0, 0);
    __builtin_amdgcn_global_load_lds((gvp)(gB + kbg * N + n0 + 64 + lane),
                                     (lvp)(&b_sm[w * 128 + 64]), 16, 0, 0);
    __syncthreads();
    bf16x8 af[4], bfr[4];
#pragma unroll
    for (int i = 0; i < 4; ++i) af[i]  = aptr[quad * 128 + wm * 64 + i * 16 + l15];
#pragma unroll
    for (int j = 0; j < 4; ++j) bfr[j] = bptr[quad * 128 + wn * 64 + j * 16 + l15];
#pragma unroll
    for (int i = 0; i < 4; ++i)
#pragma unroll
      for (int j = 0; j < 4; ++j)
        acc[i][j] = __builtin_amdgcn_mfma_f32_16x16x32_bf16(af[i], bfr[j], acc[i][j], 0, 0, 0);
    __syncthreads();
  }

#pragma unroll
  for (int i = 0; i < 4; ++i) {
    int row = m0 + wm * 64 + i * 16 + quad * 4;
#pragma unroll
    for (int j = 0; j < 4; ++j) {
      int col = n0 + wn * 64 + j * 16 + l15;
      f32x4 v = acc[i][j];
      if (BF16_OUT) {
#pragma unroll
        for (int r = 0; r < 4; ++r)
          outB[(size_t)(row + r) * N + col] = (bf16)v[r];
      } else {
        float bv = bias[col];
#pragma unroll
        for (int r = 0; r < 4; ++r)
          outF[(size_t)(row + r) * N + col] = v[r] + bv;
      }
    }
  }
}

// ---------- persistent cooperative scan over Tc timesteps ----------
// 256 blocks x 512 threads; block handles j0=2*blk and j0+1.
__global__ __launch_bounds__(512, 1) void scan_persist(
    const bf16* __restrict__ A,      // [b*Tc + trel][NVk] bf16
    const bf16* __restrict__ Ubf,    // [g][512] bf16
    const float* __restrict__ wx,    // [(b*T+t)][2048]
    const float* __restrict__ Ub,
    const float* __restrict__ Vb,
    float* __restrict__ hbuf,        // 2 x 8192 double buffer
    float* __restrict__ cst,         // 8192 c state
    float* __restrict__ out,
    int t0, int Tc) {
  cg::grid_group grid = cg::this_grid();
  __shared__ float h_s[Bk * Hk];     // 32 KB
  __shared__ bf16  U_s[8 * Hk];      // 8 KB
  __shared__ float gate_s[128];
  __shared__ float m_s[32];

  int tid = threadIdx.x;
  int j0 = blockIdx.x * 2;

  { // preload the 8 U rows this block needs: r = q*2 + jl  ->  g = q*512 + j0 + jl
    int r = tid >> 6, e = (tid & 63) * 8;
    int q = r >> 1, jl = r & 1;
    int g = q * Hk + j0 + jl;
    *reinterpret_cast<bf16x8*>(U_s + r * Hk + e) =
        *reinterpret_cast<const bf16x8*>(Ubf + (size_t)g * Hk + e);
  }

  // gate-phase invariants: dot dg = jl*64 + q*16 + b, 4 lanes each
  int dg = tid >> 2, s4 = tid & 3;
  int b_g = dg & 15, q_g = (dg >> 4) & 3, jl_g = dg >> 6;
  int g_g = q_g * Hk + j0 + jl_g;
  const bf16* Urow = U_s + (q_g * 2 + jl_g) * Hk;
  const float* hbg = h_s + b_g * Hk;
  const float* wxp = wx + (size_t)b_g * Tk * Gk + g_g;
  float ubg = Ub[g_g];

  // m-phase invariants: dot dm = jl*16 + b, 16 lanes each
  int dm = tid >> 4, sm = tid & 15;
  int b_m = dm & 15, jl_m = dm >> 4;
  const bf16* Abase = A + (size_t)b_m * Tc * NVk + (size_t)(j0 + jl_m) * Hk;
  const float* hbm = h_s + b_m * Hk;

  // c-state owners: tid<32, (jl = tid>>4, b = tid&15)
  int b_c = tid & 15, jl_c = tid >> 4;
  int j_c = j0 + jl_c;
  float c_r = 0.f, vb_c = 0.f;
  if (tid < 32) { c_r = cst[b_c * Hk + j_c]; vb_c = Vb[j_c]; }

  float4* hs4 = reinterpret_cast<float4*>(h_s);
  __syncthreads();   // U_s ready

#pragma unroll 1
  for (int t = t0; t < t0 + Tc; ++t) {
    const float4* hp4 = reinterpret_cast<const float4*>(hbuf + (t & 1) * (Bk * Hk));
#pragma unroll
    for (int i = 0; i < 4; ++i) hs4[tid + i * 512] = hp4[tid + i * 512];
    __syncthreads();

    // issue A loads early (HBM latency hides behind gate compute)
    const bf16* Ar = Abase + (size_t)(t - t0) * NVk;
    bf16x8 av[4];
#pragma unroll
    for (int i = 0; i < 4; ++i)
      av[i] = *reinterpret_cast<const bf16x8*>(Ar + (i * 16 + sm) * 8);

    // gates: U[g,:] . h[b,:]
    float ga = 0.f;
#pragma unroll
    for (int i = 0; i < 16; ++i) {
      int off = (i * 4 + s4) * 8;
      bf16x8 uv = *reinterpret_cast<const bf16x8*>(Urow + off);
      float4 h0 = *reinterpret_cast<const float4*>(hbg + off);
      float4 h1 = *reinterpret_cast<const float4*>(hbg + off + 4);
      ga += (float)uv[0] * h0.x + (float)uv[1] * h0.y + (float)uv[2] * h0.z + (float)uv[3] * h0.w
          + (float)uv[4] * h1.x + (float)uv[5] * h1.y + (float)uv[6] * h1.z + (float)uv[7] * h1.w;
    }
    ga += __shfl_xor(ga, 1);
    ga += __shfl_xor(ga, 2);
    if (s4 == 0) gate_s[dg] = ga + wxp[(size_t)t * Gk] + ubg;

    // m: A[b,t,j,:] . h[b,:]
    float ma = 0.f;
#pragma unroll
    for (int i = 0; i < 4; ++i) {
      int off = (i * 16 + sm) * 8;
      float4 h0 = *reinterpret_cast<const float4*>(hbm + off);
      float4 h1 = *reinterpret_cast<const float4*>(hbm + off + 4);
      ma += (float)av[i][0] * h0.x + (float)av[i][1] * h0.y + (float)av[i][2] * h0.z + (float)av[i][3] * h0.w
          + (float)av[i][4] * h1.x + (float)av[i][5] * h1.y + (float)av[i][6] * h1.z + (float)av[i][7] * h1.w;
    }
    ma += __shfl_xor(ma, 1);
    ma += __shfl_xor(ma, 2);
    ma += __shfl_xor(ma, 4);
    ma += __shfl_xor(ma, 8);
    if (sm == 0) m_s[dm] = ma;
    __syncthreads();

    if (tid < 32) {
      float gi = gate_s[jl_c * 64 + b_c];
      float gf = gate_s[jl_c * 64 + 16 + b_c];
      float go = gate_s[jl_c * 64 + 32 + b_c];
      float gg = gate_s[jl_c * 64 + 48 + b_c];
      float iv = 1.f / (1.f + __expf(-gi));
      float fv = 1.f / (1.f + __expf(-gf));
      float ov = 1.f / (1.f + __expf(-go));
      float gv = tanhf(gg);
      float mv = tanhf(m_s[tid] + vb_c);
      c_r = fv * c_r + iv * gv + 0.1f * mv;
      float hv = ov * tanhf(c_r);
      hbuf[((t + 1) & 1) * (Bk * Hk) + b_c * Hk + j_c] = hv;
      out[((size_t)b_c * Tk + t) * Hk + j_c] = hv;
      if (t == Tk - 1) {
        out[(size_t)Bk * Tk * Hk + b_c * Hk + j_c] = hv;                 // hT
        out[(size_t)Bk * Tk * Hk + Bk * Hk + b_c * Hk + j_c] = c_r;     // cT
      }
    }
    grid.sync();
  }
  if (tid < 32) cst[b_c * Hk + j_c] = c_r;
}

// ---------- host ----------
extern "C" void kernel_launch(void* const* d_in, const int* in_sizes, int n_in,
                              void* d_out, int out_size, void* d_ws, size_t ws_size,
                              hipStream_t stream) {
  const float* x  = (const float*)d_in[0];
  const float* Ww = (const float*)d_in[1];
  const float* Wb = (const float*)d_in[2];
  const float* Uw = (const float*)d_in[3];
  const float* Ub = (const float*)d_in[4];
  const float* Vw = (const float*)d_in[5];
  const float* Vb = (const float*)d_in[6];
  float* out = (float*)d_out;

  char* ws = (char*)d_ws;
  size_t off = 0;
  auto alloc = [&](size_t bytes) -> void* {
    void* p = ws + off;
    off = (off + bytes + 255) & ~(size_t)255;
    return p;
  };
  bf16*  xp   = (bf16*)alloc((size_t)Bk * Tk * Dk * 2);   //   4 MB packed x
  bf16*  V2p  = (bf16*)alloc((size_t)32 * NVk * 8 * 2);   // 134 MB
  bf16*  Wp   = (bf16*)alloc((size_t)32 * Gk * 8 * 2);    //   1 MB
  bf16*  Ubf  = (bf16*)alloc((size_t)Gk * Hk * 2);        //   2 MB
  float* wx   = (float*)alloc((size_t)Bk * Tk * Gk * 4);  //  67 MB
  float* hbuf = (float*)alloc((size_t)16384 * 4);
  float* cws  = (float*)alloc((size_t)8192 * 4);
  size_t fixedBytes = off;

  int Tc = 512;   // time-chunk for A; shrink until it fits the workspace
  while (Tc > 8 && fixedBytes + (size_t)Bk * Tc * Hk * Hk * 2 > ws_size) Tc >>= 1;
  bf16* A_ws = (bf16*)alloc((size_t)Bk * Tc * Hk * Hk * 2);
  int tcShift = 31 - __builtin_clz((unsigned)Tc);

  pack_x<<<32, 256, 0, stream>>>(x, xp);
  cvt_f32_bf16<<<512, 256, 0, stream>>>(Uw, Ubf, 131072);
  pack_V<<<1024, 256, 0, stream>>>(Vw, V2p);
  pack_W<<<8, 256, 0, stream>>>(Ww, Wp);
  init_state<<<64, 256, 0, stream>>>(hbuf, cws);

  // wx = x @ W^T + W_b   (M=8192, N=2048, K=256), identity row map
  gemm128<false><<<dim3(64, 16), 256, 0, stream>>>(xp, Wp, wx, nullptr, Wb,
                                                   Gk, 8192, 0, 511, 9);

  const bf16* A_p = A_ws;
  const bf16* U_p = Ubf;
  const float* wx_p = wx;
  const float* Ub_p = Ub;
  const float* Vb_p = Vb;
  float* hb_p = hbuf;
  float* c_p = cws;
  float* out_p = out;

  for (int c0 = 0; c0 < Tk; c0 += Tc) {
    // A[b, t0..t0+Tc, j, h'] = x(b,t) . V(:,d,:)   (M=16*Tc, N=262144, K=256)
    gemm128<true><<<dim3(Bk * Tc / 128, NVk / 128), 256, 0, stream>>>(
        xp, V2p, nullptr, A_ws, nullptr, NVk, 8192, c0, Tc - 1, tcShift);
    int t0a = c0, tca = Tc;
    void* sargs[10] = {(void*)&A_p, (void*)&U_p, (void*)&wx_p, (void*)&Ub_p,
                       (void*)&Vb_p, (void*)&hb_p, (void*)&c_p, (void*)&out_p,
                       (void*)&t0a, (void*)&tca};
    hipLaunchCooperativeKernel(reinterpret_cast<void*>(&scan_persist),
                               dim3(256), dim3(512), sargs, 0, stream);
  }
}

// Round 3
// 5955.032 us; speedup vs baseline: 3.4545x; 3.4545x over previous
//
#include <hip/hip_runtime.h>
#include <cstdint>
#include <cstddef>

#define Dk 256
#define Hk 512
#define Bk 16
#define Tk 512
#define Gk 2048      // 4H
#define NVk 262144   // H*H

typedef __bf16 bf16;
typedef __bf16 bf16x8 __attribute__((ext_vector_type(8)));
typedef float  f32x4  __attribute__((ext_vector_type(4)));
typedef const __attribute__((address_space(1))) void* gvp;
typedef __attribute__((address_space(3))) void* lvp;

__device__ __forceinline__ float bflo(unsigned u) {
  u <<= 16; return __builtin_bit_cast(float, u);
}
__device__ __forceinline__ float bfhi(unsigned u) {
  u &= 0xffff0000u; return __builtin_bit_cast(float, u);
}

// ---------- prep kernels ----------
__global__ __launch_bounds__(256) void cvt_f32_bf16(const float* __restrict__ in,
                                                    bf16* __restrict__ out, int n8) {
  int i = blockIdx.x * 256 + threadIdx.x;
  if (i >= n8) return;
  const float4* p = reinterpret_cast<const float4*>(in) + (size_t)i * 2;
  float4 a = p[0], b = p[1];
  bf16x8 v;
  v[0] = (bf16)a.x; v[1] = (bf16)a.y; v[2] = (bf16)a.z; v[3] = (bf16)a.w;
  v[4] = (bf16)b.x; v[5] = (bf16)b.y; v[6] = (bf16)b.z; v[7] = (bf16)b.w;
  *reinterpret_cast<bf16x8*>(out + (size_t)i * 8) = v;
}

// V_w[j][d*512+h'] (fp32) -> packed B: V2p[(d/8)][n=(j,h')][d%8] (bf16)
__global__ __launch_bounds__(256) void pack_V(const float* __restrict__ Vw,
                                              bf16* __restrict__ V2p) {
  int n = blockIdx.x * 256 + threadIdx.x;        // 0..262143
  int j = n >> 9, hp = n & 511;
  const float* src = Vw + (size_t)j * 131072 + hp;
  for (int kb = 0; kb < 32; ++kb) {
    bf16x8 v;
#pragma unroll
    for (int r = 0; r < 8; ++r) v[r] = (bf16)src[(size_t)(kb * 8 + r) * 512];
    *reinterpret_cast<bf16x8*>(V2p + ((size_t)kb * NVk + n) * 8) = v;
  }
}

// W_w[g][d] (fp32) -> packed B: Wp[(d/8)][g][d%8] (bf16)
__global__ __launch_bounds__(256) void pack_W(const float* __restrict__ Ww,
                                              bf16* __restrict__ Wp) {
  int g = blockIdx.x * 256 + threadIdx.x;        // 0..2047
  const float* src = Ww + (size_t)g * 256;
  for (int kb = 0; kb < 32; ++kb) {
    bf16x8 v;
#pragma unroll
    for (int r = 0; r < 8; ++r) v[r] = (bf16)src[kb * 8 + r];
    *reinterpret_cast<bf16x8*>(Wp + ((size_t)kb * Gk + g) * 8) = v;
  }
}

// x[row][d] (fp32, row=b*512+t) -> packed A: xp[(d/8)][row][d%8] (bf16)
__global__ __launch_bounds__(256) void pack_x(const float* __restrict__ x,
                                              bf16* __restrict__ xp) {
  int row = blockIdx.x * 256 + threadIdx.x;      // 0..8191
  const float* src = x + (size_t)row * 256;
  for (int kb = 0; kb < 32; ++kb) {
    bf16x8 v;
#pragma unroll
    for (int r = 0; r < 8; ++r) v[r] = (bf16)src[kb * 8 + r];
    *reinterpret_cast<bf16x8*>(xp + ((size_t)kb * 8192 + row) * 8) = v;
  }
}

__global__ __launch_bounds__(256) void init_state(bf16* __restrict__ hbuf,
                                                  float* __restrict__ cws) {
  int i = blockIdx.x * 256 + threadIdx.x;
  if (i < 16384) hbuf[i] = (bf16)0.f;
  if (i < 8192)  cws[i]  = 0.f;
}

// ---------- 128x128 tile MFMA GEMM with global_load_lds staging ----------
// A packed [k/8][Mtot][k%8], row map: b = m>>tcShift ; xrow = b*512 + t0 + (m&tcMask)
// B packed [k/8][N][k%8]
template <bool BF16_OUT>
__global__ __launch_bounds__(256) void gemm128(const bf16* __restrict__ Ap,
                                               const bf16* __restrict__ Bp,
                                               float* __restrict__ outF,
                                               bf16* __restrict__ outB,
                                               const float* __restrict__ bias,
                                               const float* __restrict__ bias2,
                                               int N, int Mtot,
                                               int t0, int tcMask, int tcShift) {
  __shared__ uint4 a_sm[512];   // [kb(4)][m(128)] 16B each
  __shared__ uint4 b_sm[512];   // [kb(4)][n(128)]
  int tid = threadIdx.x;
  int lane = tid & 63, w = tid >> 6;
  int quad = lane >> 4, l15 = lane & 15;
  int wm = w >> 1, wn = w & 1;
  int m0 = blockIdx.x * 128, n0 = blockIdx.y * 128;

  f32x4 acc[4][4];
#pragma unroll
  for (int i = 0; i < 4; ++i)
#pragma unroll
    for (int j = 0; j < 4; ++j) acc[i][j] = (f32x4){0.f, 0.f, 0.f, 0.f};

  int gm0 = m0 + lane, gm1 = m0 + 64 + lane;
  int xr0 = ((gm0 >> tcShift) << 9) + t0 + (gm0 & tcMask);
  int xr1 = ((gm1 >> tcShift) << 9) + t0 + (gm1 & tcMask);
  const uint4* gA = reinterpret_cast<const uint4*>(Ap);
  const uint4* gB = reinterpret_cast<const uint4*>(Bp);

  const bf16x8* aptr = reinterpret_cast<const bf16x8*>(a_sm);
  const bf16x8* bptr = reinterpret_cast<const bf16x8*>(b_sm);

  for (int kk = 0; kk < 8; ++kk) {
    size_t kbg = (size_t)(kk * 4 + w);
    __builtin_amdgcn_global_load_lds((gvp)(gA + kbg * Mtot + xr0),
                                     (lvp)(&a_sm[w * 128]), 16, 0, 0);
    __builtin_amdgcn_global_load_lds((gvp)(gA + kbg * Mtot + xr1),
                                     (lvp)(&a_sm[w * 128 + 64]), 16, 0, 0);
    __builtin_amdgcn_global_load_lds((gvp)(gB + kbg * N + n0 + lane),
                                     (lvp)(&b_sm[w * 128]), 16, 0, 0);
    __builtin_amdgcn_global_load_lds((gvp)(gB + kbg * N + n0 + 64 + lane),
                                     (lvp)(&b_sm[w * 128 + 64]), 16, 0, 0);
    __syncthreads();
    bf16x8 af[4], bfr[4];
#pragma unroll
    for (int i = 0; i < 4; ++i) af[i]  = aptr[quad * 128 + wm * 64 + i * 16 + l15];
#pragma unroll
    for (int j = 0; j < 4; ++j) bfr[j] = bptr[quad * 128 + wn * 64 + j * 16 + l15];
#pragma unroll
    for (int i = 0; i < 4; ++i)
#pragma unroll
      for (int j = 0; j < 4; ++j)
        acc[i][j] = __builtin_amdgcn_mfma_f32_16x16x32_bf16(af[i], bfr[j], acc[i][j], 0, 0, 0);
    __syncthreads();
  }

#pragma unroll
  for (int i = 0; i < 4; ++i) {
    int row = m0 + wm * 64 + i * 16 + quad * 4;
#pragma unroll
    for (int j = 0; j < 4; ++j) {
      int col = n0 + wn * 64 + j * 16 + l15;
      f32x4 v = acc[i][j];
      if (BF16_OUT) {
#pragma unroll
        for (int r = 0; r < 4; ++r)
          outB[(size_t)(row + r) * N + col] = (bf16)v[r];
      } else {
        float bv = bias[col] + bias2[col];
#pragma unroll
        for (int r = 0; r < 4; ++r)
          outF[(size_t)(row + r) * N + col] = v[r] + bv;
      }
    }
  }
}

// ---------- one scan timestep, conflict-free ----------
// 512 blocks (one j each) x 256 threads. 16 lanes per dot, lane sm owns a
// contiguous bf16x8 per K-iter -> every 16-lane phase reads 256 contiguous B.
__global__ __launch_bounds__(256) void scan_step3(
    const bf16* __restrict__ A,     // chunk base [b*Tc + trel][NVk]
    int trel, int Tc,
    const bf16* __restrict__ Ubf,   // [g][512]
    const float* __restrict__ wx,   // [(b*T+t)][2048], bias already folded
    const float* __restrict__ Vb,
    const bf16* __restrict__ hprev, // [b][512] bf16
    bf16* __restrict__ hnext,
    float* __restrict__ cst,        // [b][512] fp32
    float* __restrict__ out, int t) {
  __shared__ bf16 U_s[4 * Hk];      // 4 KB
  __shared__ float gate_s[64];
  __shared__ float m_s[16];
  int tid = threadIdx.x;
  int j = blockIdx.x;
  int b = tid >> 4, sm = tid & 15;

  // A loads first (HBM latency)
  const bf16* Ar = A + ((size_t)b * Tc + trel) * NVk + (size_t)j * Hk;
  uint4 av[4];
#pragma unroll
  for (int i = 0; i < 4; ++i)
    av[i] = *reinterpret_cast<const uint4*>(Ar + i * 128 + sm * 8);

  // h loads (L2/L3, 16 KB per block, coalesced 256B segments)
  uint4 hv[4];
#pragma unroll
  for (int i = 0; i < 4; ++i)
    hv[i] = *reinterpret_cast<const uint4*>(hprev + b * Hk + i * 128 + sm * 8);

  // stage the 4 U rows this block needs: g = r*512 + j
  {
    int r = tid >> 6, e = (tid & 63) * 8;
    *reinterpret_cast<uint4*>(U_s + r * Hk + e) =
        *reinterpret_cast<const uint4*>(Ubf + ((size_t)r * Hk + j) * Hk + e);
  }
  __syncthreads();

  // unpack h once to fp32 (reused by all 5 dots)
  float hf[4][8];
#pragma unroll
  for (int i = 0; i < 4; ++i) {
    unsigned ux = hv[i].x, uy = hv[i].y, uz = hv[i].z, uw = hv[i].w;
    hf[i][0] = bflo(ux); hf[i][1] = bfhi(ux);
    hf[i][2] = bflo(uy); hf[i][3] = bfhi(uy);
    hf[i][4] = bflo(uz); hf[i][5] = bfhi(uz);
    hf[i][6] = bflo(uw); hf[i][7] = bfhi(uw);
  }

  float accs[5] = {0.f, 0.f, 0.f, 0.f, 0.f};
  const uint4* Uq = reinterpret_cast<const uint4*>(U_s);
#pragma unroll
  for (int i = 0; i < 4; ++i) {
#pragma unroll
    for (int q = 0; q < 4; ++q) {
      uint4 u = Uq[q * 64 + i * 16 + sm];   // broadcast across the 4 dot groups
      accs[q] += bflo(u.x) * hf[i][0] + bfhi(u.x) * hf[i][1]
               + bflo(u.y) * hf[i][2] + bfhi(u.y) * hf[i][3]
               + bflo(u.z) * hf[i][4] + bfhi(u.z) * hf[i][5]
               + bflo(u.w) * hf[i][6] + bfhi(u.w) * hf[i][7];
    }
    uint4 a = av[i];
    accs[4] += bflo(a.x) * hf[i][0] + bfhi(a.x) * hf[i][1]
             + bflo(a.y) * hf[i][2] + bfhi(a.y) * hf[i][3]
             + bflo(a.z) * hf[i][4] + bfhi(a.z) * hf[i][5]
             + bflo(a.w) * hf[i][6] + bfhi(a.w) * hf[i][7];
  }
#pragma unroll
  for (int d = 1; d < 16; d <<= 1) {
#pragma unroll
    for (int k = 0; k < 5; ++k) accs[k] += __shfl_xor(accs[k], d);
  }
  if (sm == 0) {
    const float* wxr = wx + ((size_t)b * Tk + t) * Gk + j;
#pragma unroll
    for (int q = 0; q < 4; ++q) gate_s[q * 16 + b] = accs[q] + wxr[q * Hk];
    m_s[b] = accs[4];
  }
  __syncthreads();

  if (tid < 16) {
    int bb = tid;
    float gi = gate_s[bb], gf = gate_s[16 + bb];
    float go = gate_s[32 + bb], gg = gate_s[48 + bb];
    float iv = 1.f / (1.f + __expf(-gi));
    float fv = 1.f / (1.f + __expf(-gf));
    float ov = 1.f / (1.f + __expf(-go));
    float gv = tanhf(gg);
    float mv = tanhf(m_s[bb] + Vb[j]);
    int idx = bb * Hk + j;
    float c = fv * cst[idx] + iv * gv + 0.1f * mv;
    cst[idx] = c;
    float h = ov * tanhf(c);
    hnext[idx] = (bf16)h;
    out[((size_t)bb * Tk + t) * Hk + j] = h;
    if (t == Tk - 1) {
      out[(size_t)Bk * Tk * Hk + idx] = h;                 // hT
      out[(size_t)Bk * Tk * Hk + Bk * Hk + idx] = c;       // cT
    }
  }
}

// ---------- host ----------
extern "C" void kernel_launch(void* const* d_in, const int* in_sizes, int n_in,
                              void* d_out, int out_size, void* d_ws, size_t ws_size,
                              hipStream_t stream) {
  const float* x  = (const float*)d_in[0];
  const float* Ww = (const float*)d_in[1];
  const float* Wb = (const float*)d_in[2];
  const float* Uw = (const float*)d_in[3];
  const float* Ub = (const float*)d_in[4];
  const float* Vw = (const float*)d_in[5];
  const float* Vb = (const float*)d_in[6];
  float* out = (float*)d_out;

  char* ws = (char*)d_ws;
  size_t off = 0;
  auto alloc = [&](size_t bytes) -> void* {
    void* p = ws + off;
    off = (off + bytes + 255) & ~(size_t)255;
    return p;
  };
  bf16*  xp   = (bf16*)alloc((size_t)Bk * Tk * Dk * 2);   //   4 MB packed x
  bf16*  V2p  = (bf16*)alloc((size_t)32 * NVk * 8 * 2);   // 134 MB
  bf16*  Wp   = (bf16*)alloc((size_t)32 * Gk * 8 * 2);    //   1 MB
  bf16*  Ubf  = (bf16*)alloc((size_t)Gk * Hk * 2);        //   2 MB
  float* wx   = (float*)alloc((size_t)Bk * Tk * Gk * 4);  //  67 MB
  bf16*  hbuf = (bf16*)alloc((size_t)16384 * 2);          // double buffer, bf16
  float* cws  = (float*)alloc((size_t)8192 * 4);
  size_t fixedBytes = off;

  int Tc = 512;   // time-chunk for A; shrink until it fits the workspace
  while (Tc > 8 && fixedBytes + (size_t)Bk * Tc * Hk * Hk * 2 > ws_size) Tc >>= 1;
  bf16* A_ws = (bf16*)alloc((size_t)Bk * Tc * Hk * Hk * 2);
  int tcShift = 31 - __builtin_clz((unsigned)Tc);

  pack_x<<<32, 256, 0, stream>>>(x, xp);
  cvt_f32_bf16<<<512, 256, 0, stream>>>(Uw, Ubf, 131072);
  pack_V<<<1024, 256, 0, stream>>>(Vw, V2p);
  pack_W<<<8, 256, 0, stream>>>(Ww, Wp);
  init_state<<<64, 256, 0, stream>>>(hbuf, cws);

  // wx = x @ W^T + (W_b + U_b)   (M=8192, N=2048, K=256), identity row map
  gemm128<false><<<dim3(64, 16), 256, 0, stream>>>(xp, Wp, wx, nullptr, Wb, Ub,
                                                   Gk, 8192, 0, 511, 9);

  for (int c0 = 0; c0 < Tk; c0 += Tc) {
    // A[b, t0..t0+Tc, j, h'] = x(b,t) . V(:,d,:)   (M=16*Tc, N=262144, K=256)
    gemm128<true><<<dim3(Bk * Tc / 128, NVk / 128), 256, 0, stream>>>(
        xp, V2p, nullptr, A_ws, nullptr, nullptr, NVk, 8192, c0, Tc - 1, tcShift);
    for (int t = c0; t < c0 + Tc; ++t) {
      scan_step3<<<512, 256, 0, stream>>>(
          A_ws, t - c0, Tc, Ubf, wx, Vb,
          hbuf + (t & 1) * 8192, hbuf + ((t + 1) & 1) * 8192,
          cws, out, t);
    }
  }
}